// Round 12
// baseline (248.148 us; speedup 1.0000x reference)
//
#include <hip/hip_runtime.h>
#include <math.h>

#define NPTS 4096
#define CC 0.7213475204444817f   // log2(e)/2 : exp(-s^2/2) = 2^(-CC*s^2)

// ---------------- feature MLP: coords[B,N,3] -> outT[b][h][n] (transposed) ----------------
__global__ __launch_bounds__(256) void feat_kernel(
    const float* __restrict__ coords, const float* __restrict__ W1,
    const float* __restrict__ b1, const float* __restrict__ W2,
    const float* __restrict__ b2, float* __restrict__ outT, int npts)
{
  __shared__ float sW1[3 * 64], sb1[64], sW2[64 * 64], sb2[64];
  const int tid = threadIdx.x;
  for (int i = tid; i < 192; i += 256) sW1[i] = W1[i];
  if (tid < 64) { sb1[tid] = b1[tid]; sb2[tid] = b2[tid]; }
  for (int i = tid; i < 4096; i += 256) sW2[i] = W2[i];
  __syncthreads();

  const int p  = blockIdx.x * 64 + (tid & 63);   // point index (consecutive threads -> consecutive n)
  const int qh = (tid >> 6) * 16;                // h-quarter handled by this thread
  if (p >= npts) return;
  const float c0 = coords[p * 3 + 0], c1 = coords[p * 3 + 1], c2 = coords[p * 3 + 2];

  float hid[64];
  #pragma unroll
  for (int j = 0; j < 64; ++j)
    hid[j] = fmaxf(0.f, fmaf(c0, sW1[j], fmaf(c1, sW1[64 + j], fmaf(c2, sW1[128 + j], sb1[j]))));

  float acc[16];
  #pragma unroll
  for (int h = 0; h < 16; ++h) acc[h] = sb2[qh + h];
  for (int j = 0; j < 64; ++j) {
    const float hj = hid[j];
    const float4* wrow = (const float4*)&sW2[j * 64 + qh];
    #pragma unroll
    for (int hq = 0; hq < 4; ++hq) {
      float4 wv = wrow[hq];
      acc[hq * 4 + 0] = fmaf(hj, wv.x, acc[hq * 4 + 0]);
      acc[hq * 4 + 1] = fmaf(hj, wv.y, acc[hq * 4 + 1]);
      acc[hq * 4 + 2] = fmaf(hj, wv.z, acc[hq * 4 + 2]);
      acc[hq * 4 + 3] = fmaf(hj, wv.w, acc[hq * 4 + 3]);
    }
  }
  const int b = p / NPTS, n = p % NPTS;
  #pragma unroll
  for (int h = 0; h < 16; ++h)
    outT[(size_t)(b * 64 + qh + h) * NPTS + n] = acc[h];
}

// ---------------- Vo kernel: Vo[b,n] = MLP_v(values)[b,n,:] . Wo ----------------
__global__ __launch_bounds__(256) void vo_kernel(
    const float* __restrict__ values, const float* __restrict__ Wv1,
    const float* __restrict__ bv1, const float* __restrict__ Wv2,
    const float* __restrict__ bv2, const float* __restrict__ Wo,
    float* __restrict__ VoOut, int npts)
{
  __shared__ float sWvO[64], sW1[64], sb1[64], sc0;
  const int tid = threadIdx.x;
  if (tid < 64) {
    float a = 0.f;
    for (int h = 0; h < 64; ++h) a = fmaf(Wv2[tid * 64 + h], Wo[h], a);
    sWvO[tid] = a;
    sW1[tid] = Wv1[tid];
    sb1[tid] = bv1[tid];
  } else if (tid == 64) {
    float a = 0.f;
    for (int h = 0; h < 64; ++h) a = fmaf(bv2[h], Wo[h], a);
    sc0 = a;
  }
  __syncthreads();
  const int p = blockIdx.x * 256 + tid;
  if (p >= npts) return;
  const float v = values[p];
  float a = sc0;
  #pragma unroll 8
  for (int j = 0; j < 64; ++j)
    a = fmaf(fmaxf(0.f, fmaf(v, sW1[j], sb1[j])), sWvO[j], a);
  VoOut[p] = a;
}

// ---------------- main attention kernel ----------------
// grid: B*128 blocks (one 32-m tile each), 1024 threads (16 waves),
// 2 blocks/CU -> 32 waves/CU = 8 waves/SIMD.
// Rounds 8-11 synthesis: four structural variants all land 208-230 us =
// ~1.1-1.3 wave-instr/cy/CU — the same practical ISSUE ceiling m07's FMA
// ubench hit (66% of 2cy peak). Floor ~185 us incl. overhead. The residual
// gap vs 208 is phase-boundary stalls at only 4 waves/SIMD. This round:
// double TLP to 8 waves/SIMD (LDS 74 KB/block so 2 blocks/CU; VGPR budget
// pinned to 64 via amdgpu_waves_per_eu(8) — demand ~56 proven in r11).
// Inner loop identical to r11 (fence-free global-K + interleaved 2-pair asm).
__global__ void __launch_bounds__(1024)
__attribute__((amdgpu_waves_per_eu(8)))
attn_kernel(
    const float* __restrict__ Kt, const float* __restrict__ Qt,
    const float* __restrict__ Vo, const float* __restrict__ bo,
    float* __restrict__ out)
{
  __shared__ float Qs[64 * 32];      // [h][m_local]  8 KB
  __shared__ float MtL[512];         // [w][m_local]  2 KB
  __shared__ float numL[8192];       // [w][j*64+lane] running numerator 32 KB
  __shared__ float denL[8192];       // [w][j*64+lane] running denominator 32 KB

  const int b    = blockIdx.x >> 7;  // 128 m-tiles per batch
  const int m0   = (blockIdx.x & 127) << 5;
  const int tid  = threadIdx.x;
  const int w    = tid >> 6;         // 0..15
  const int lane = tid & 63;
  const int lm = lane >> 4;          // 0..3 : m-group (8 m each -> 32 m)
  const int ln = lane & 15;          // 0..15: n-group (4 n each -> 64 n/wave)

  const float* __restrict__ KtB = Kt + (size_t)b * 64 * NPTS;
  const float* __restrict__ QtB = Qt + (size_t)b * 64 * NPTS;
  const float* __restrict__ VoB = Vo + (size_t)b * NPTS;

  { // stage Q tile (64h x 32m) into LDS; zero own stats
    const int h = tid >> 4, c = (tid & 15) * 2;
    *(float2*)&Qs[h * 32 + c] = *(const float2*)&QtB[(size_t)h * NPTS + m0 + c];
    #pragma unroll
    for (int j = 0; j < 8; ++j) {
      numL[w * 512 + j * 64 + lane] = 0.f;
      denL[w * 512 + j * 64 + lane] = 0.f;
    }
  }
  __syncthreads();

  float acc[32];
  float Mt[8];
  #pragma unroll
  for (int x = 0; x < 32; ++x) acc[x] = 0.f;
  #pragma unroll
  for (int j = 0; j < 8; ++j) Mt[j] = __builtin_inff();

  const float* __restrict__ Kb = KtB + w * 64 + ln * 4;  // per-lane K base
  const float* __restrict__ Qb = &Qs[lm * 8];            // per-lane Q base

  for (int I = 0; I < 4; ++I) {          // n-iterations (1024 n each; wave owns 64)
    const float* __restrict__ Kn = Kb + I * 1024;
    #pragma unroll 2
    for (int h = 0; h < 64; ++h) {       // stream over the feature dim
      float q[8], k[4];
      *(float4*)&k[0] = *(const float4*)(Kn + (size_t)h * NPTS);  // VMEM, L2-hot
      *(float4*)&q[0] = *(const float4*)(Qb + h * 32);            // LDS
      *(float4*)&q[4] = *(const float4*)(Qb + h * 32 + 4);
      #pragma unroll
      for (int j = 0; j < 8; ++j) {
        #pragma unroll
        for (int i = 0; i < 4; i += 2) {
          float d0, d1;
          // 2 pairs interleaved: deps 4cy apart -> zero single-wave stalls
          asm("v_sub_f32 %0, %4, %6\n\t"
              "v_sub_f32 %1, %5, %6\n\t"
              "v_add_f32 %2, %2, |%0|\n\t"
              "v_add_f32 %3, %3, |%1|"
              : "=&v"(d0), "=&v"(d1),
                "+v"(acc[j * 4 + i]), "+v"(acc[j * 4 + i + 1])
              : "v"(k[i]), "v"(k[i + 1]), "v"(q[j]));
        }
      }
    }

    { // epilogue for iteration I: online softmax update (min s -> min s^2)
      float vo[4];
      const int vb = I * 1024 + w * 64 + ln * 4;
      *(float4*)&vo[0] = *(const float4*)&VoB[vb];   // global, L2-hot
      #pragma unroll
      for (int j = 0; j < 8; ++j) {
        // acc >= 0, so min(s^2) == (min s)^2
        float rmin = fminf(fminf(acc[j*4+0], acc[j*4+1]), fminf(acc[j*4+2], acc[j*4+3]));
        rmin = fminf(rmin, __shfl_xor(rmin, 1));
        rmin = fminf(rmin, __shfl_xor(rmin, 2));
        rmin = fminf(rmin, __shfl_xor(rmin, 4));
        rmin = fminf(rmin, __shfl_xor(rmin, 8));
        const float nM = fminf(Mt[j], rmin * rmin);
        const float sc = __builtin_amdgcn_exp2f(CC * (nM - Mt[j])); // inf start -> 0
        const int slot = w * 512 + j * 64 + lane;
        float nm = numL[slot] * sc;
        float dn = denL[slot] * sc;
        Mt[j] = nM;
        const float base = CC * nM;
        #pragma unroll
        for (int i = 0; i < 4; ++i) {
          const float a = acc[j * 4 + i];
          const float wgt = __builtin_amdgcn_exp2f(fmaf(-CC, a * a, base));
          dn += wgt;
          nm = fmaf(wgt, vo[i], nm);
          acc[j * 4 + i] = 0.f;
        }
        numL[slot] = nm;
        denL[slot] = dn;
      }
    }
  }

  // publish per-wave Mt (uniform across the 16 ln-lanes of each m)
  if (ln == 0) {
    #pragma unroll
    for (int j = 0; j < 8; ++j)
      MtL[w * 32 + lm * 8 + j] = Mt[j];
  }
  __syncthreads();

  if (tid < 32) {                  // merge the 16 waves' partial softmax states
    const int m = tid;             // m = lm*8 + j  ->  j = m&7, lm = m>>3
    float M = __builtin_inff();
    #pragma unroll
    for (int ww = 0; ww < 16; ++ww) M = fminf(M, MtL[ww * 32 + m]);
    float Ns = 0.f, Ds = 0.f;
    #pragma unroll
    for (int ww = 0; ww < 16; ++ww) {
      const float f = __builtin_amdgcn_exp2f(CC * (M - MtL[ww * 32 + m]));
      float ns = 0.f, ds = 0.f;
      #pragma unroll
      for (int l = 0; l < 16; ++l) {
        const int idx = ww * 512 + (m & 7) * 64 + (m >> 3) * 16 + l;
        ns += numL[idx];
        ds += denL[idx];
      }
      Ns = fmaf(ns, f, Ns);
      Ds = fmaf(ds, f, Ds);
    }
    out[(size_t)b * NPTS + m0 + m] = Ns / Ds + bo[0];
  }
}

extern "C" void kernel_launch(void* const* d_in, const int* in_sizes, int n_in,
                              void* d_out, int out_size, void* d_ws, size_t ws_size,
                              hipStream_t stream)
{
  const float* coords_f = (const float*)d_in[0];
  const float* values_f = (const float*)d_in[1];
  const float* coords_t = (const float*)d_in[2];
  const float* Wk1 = (const float*)d_in[3];
  const float* bk1 = (const float*)d_in[4];
  const float* Wk2 = (const float*)d_in[5];
  const float* bk2 = (const float*)d_in[6];
  const float* Wq1 = (const float*)d_in[7];
  const float* bq1 = (const float*)d_in[8];
  const float* Wq2 = (const float*)d_in[9];
  const float* bq2 = (const float*)d_in[10];
  const float* Wv1 = (const float*)d_in[11];
  const float* bv1 = (const float*)d_in[12];
  const float* Wv2 = (const float*)d_in[13];
  const float* bv2 = (const float*)d_in[14];
  const float* Wo  = (const float*)d_in[15];
  const float* bo  = (const float*)d_in[16];

  const int B    = in_sizes[0] / (NPTS * 3);
  const int npts = B * NPTS;

  float* Kt  = (float*)d_ws;                       // [B][64][N]
  float* Qt  = Kt + (size_t)B * 64 * NPTS;         // [B][64][M]
  float* VoW = Qt + (size_t)B * 64 * NPTS;         // [B][N]

  feat_kernel<<<npts / 64, 256, 0, stream>>>(coords_f, Wk1, bk1, Wk2, bk2, Kt, npts);
  feat_kernel<<<npts / 64, 256, 0, stream>>>(coords_t, Wq1, bq1, Wq2, bq2, Qt, npts);
  vo_kernel<<<npts / 256, 256, 0, stream>>>(values_f, Wv1, bv1, Wv2, bv2, Wo, VoW, npts);
  attn_kernel<<<B * 128, 1024, 0, stream>>>(Kt, Qt, VoW, bo, (float*)d_out);
}

// Round 13
// 224.994 us; speedup vs baseline: 1.1029x; 1.1029x over previous
//
#include <hip/hip_runtime.h>
#include <math.h>

#define NPTS 4096
#define CC  0.7213475204444817f      // log2(e)/2 : exp(-s^2/2) = 2^(-CC*s^2)
#define QSC 524288.0f                // 2^19 fixed-point scale
#define QIN (1.0f / 524288.0f)       // 2^-19
#define CCI (CC * QIN * QIN)         // CC in (integer s)^2 units

__device__ __forceinline__ unsigned umin2(unsigned a, unsigned b) { return a < b ? a : b; }

// ---------------- feature MLP: coords[B,N,3] -> outT[b][h][n] (u32 fixed-point, transposed) ----
__global__ __launch_bounds__(256) void feat_kernel(
    const float* __restrict__ coords, const float* __restrict__ W1,
    const float* __restrict__ b1, const float* __restrict__ W2,
    const float* __restrict__ b2, unsigned* __restrict__ outT, int npts)
{
  __shared__ float sW1[3 * 64], sb1[64], sW2[64 * 64], sb2[64];
  const int tid = threadIdx.x;
  for (int i = tid; i < 192; i += 256) sW1[i] = W1[i];
  if (tid < 64) { sb1[tid] = b1[tid]; sb2[tid] = b2[tid]; }
  for (int i = tid; i < 4096; i += 256) sW2[i] = W2[i];
  __syncthreads();

  const int p  = blockIdx.x * 64 + (tid & 63);   // point index
  const int qh = (tid >> 6) * 16;                // h-quarter handled by this thread
  if (p >= npts) return;
  const float c0 = coords[p * 3 + 0], c1 = coords[p * 3 + 1], c2 = coords[p * 3 + 2];

  float hid[64];
  #pragma unroll
  for (int j = 0; j < 64; ++j)
    hid[j] = fmaxf(0.f, fmaf(c0, sW1[j], fmaf(c1, sW1[64 + j], fmaf(c2, sW1[128 + j], sb1[j]))));

  float acc[16];
  #pragma unroll
  for (int h = 0; h < 16; ++h) acc[h] = sb2[qh + h];
  for (int j = 0; j < 64; ++j) {
    const float hj = hid[j];
    const float4* wrow = (const float4*)&sW2[j * 64 + qh];
    #pragma unroll
    for (int hq = 0; hq < 4; ++hq) {
      float4 wv = wrow[hq];
      acc[hq * 4 + 0] = fmaf(hj, wv.x, acc[hq * 4 + 0]);
      acc[hq * 4 + 1] = fmaf(hj, wv.y, acc[hq * 4 + 1]);
      acc[hq * 4 + 2] = fmaf(hj, wv.z, acc[hq * 4 + 2]);
      acc[hq * 4 + 3] = fmaf(hj, wv.w, acc[hq * 4 + 3]);
    }
  }
  const int b = p / NPTS, n = p % NPTS;
  #pragma unroll
  for (int h = 0; h < 16; ++h)
    outT[(size_t)(b * 64 + qh + h) * NPTS + n] =
        (unsigned)((int)rintf(acc[h] * QSC) + (1 << 30));
}

// ---------------- Vo kernel: Vo[b,n] = MLP_v(values)[b,n,:] . Wo ----------------
__global__ __launch_bounds__(256) void vo_kernel(
    const float* __restrict__ values, const float* __restrict__ Wv1,
    const float* __restrict__ bv1, const float* __restrict__ Wv2,
    const float* __restrict__ bv2, const float* __restrict__ Wo,
    float* __restrict__ VoOut, int npts)
{
  __shared__ float sWvO[64], sW1[64], sb1[64], sc0;
  const int tid = threadIdx.x;
  if (tid < 64) {
    float a = 0.f;
    for (int h = 0; h < 64; ++h) a = fmaf(Wv2[tid * 64 + h], Wo[h], a);
    sWvO[tid] = a;
    sW1[tid] = Wv1[tid];
    sb1[tid] = bv1[tid];
  } else if (tid == 64) {
    float a = 0.f;
    for (int h = 0; h < 64; ++h) a = fmaf(bv2[h], Wo[h], a);
    sc0 = a;
  }
  __syncthreads();
  const int p = blockIdx.x * 256 + tid;
  if (p >= npts) return;
  const float v = values[p];
  float a = sc0;
  #pragma unroll 8
  for (int j = 0; j < 64; ++j)
    a = fmaf(fmaxf(0.f, fmaf(v, sW1[j], sb1[j])), sWvO[j], a);
  VoOut[p] = a;
}

// ---------------- main attention kernel ----------------
// grid: B*64 blocks (one 64-m tile each), 1024 threads (16 waves).
// Rounds 8-12 synthesis: every float variant (2+ VALU slots/pair) pins at
// 208-234 us — an instruction-ISSUE wall. This round halves the instruction
// stream algorithmically: K/Q quantized to u32 fixed-point (2^19 scale,
// 2^30 bias) so the inner update is ONE v_sad_u32 (|k-q|+acc) per pair.
// Skeleton = r11's proven clean-allocation structure (acc[32] 8m x 4n,
// fence-free global-K, Q in LDS).
__global__ void __launch_bounds__(1024)
attn_kernel(
    const unsigned* __restrict__ Kt, const unsigned* __restrict__ Qt,
    const float* __restrict__ Vo, const float* __restrict__ bo,
    float* __restrict__ out)
{
  __shared__ unsigned Qs[64 * 64];   // [h][m_local]  16 KB (u32 fixed-point)
  __shared__ float MtL[1024];        // [w][m_local]  4 KB
  __shared__ float numL[8192];       // [w][j*64+lane] running numerator 32 KB
  __shared__ float denL[8192];       // [w][j*64+lane] running denominator 32 KB

  const int b    = blockIdx.x >> 6;
  const int m0   = (blockIdx.x & 63) << 6;
  const int tid  = threadIdx.x;
  const int w    = tid >> 6;         // 0..15
  const int lane = tid & 63;
  const int lm = lane >> 3, ln = lane & 7;

  const unsigned* __restrict__ KtB = Kt + (size_t)b * 64 * NPTS;
  const unsigned* __restrict__ QtB = Qt + (size_t)b * 64 * NPTS;
  const float*    __restrict__ VoB = Vo + (size_t)b * NPTS;

  { // stage Q tile into LDS (coalesced uint4); zero own stats
    const int h = tid >> 4, c16 = (tid & 15) * 4;
    *(uint4*)&Qs[h * 64 + c16] = *(const uint4*)&QtB[(size_t)h * NPTS + m0 + c16];
    #pragma unroll
    for (int j = 0; j < 8; ++j) {
      numL[w * 512 + j * 64 + lane] = 0.f;
      denL[w * 512 + j * 64 + lane] = 0.f;
    }
  }
  __syncthreads();

  unsigned acc[32];
  float Mt[8];
  #pragma unroll
  for (int x = 0; x < 32; ++x) acc[x] = 0u;
  #pragma unroll
  for (int j = 0; j < 8; ++j) Mt[j] = __builtin_inff();

  const unsigned* __restrict__ Kb = KtB + w * 32 + ln * 4;  // per-lane K base
  const unsigned* __restrict__ Qb = &Qs[lm * 8];            // per-lane Q base

  for (int I = 0; I < 8; ++I) {          // n-iterations (512 n each; wave owns 32)
    const unsigned* __restrict__ Kn = Kb + I * 512;
    #pragma unroll 2
    for (int h = 0; h < 64; ++h) {       // stream over the feature dim
      unsigned q[8], k[4];
      *(uint4*)&k[0] = *(const uint4*)(Kn + (size_t)h * NPTS);  // VMEM, L2-hot
      *(uint4*)&q[0] = *(const uint4*)(Qb + h * 64);            // LDS
      *(uint4*)&q[4] = *(const uint4*)(Qb + h * 64 + 4);
      #pragma unroll
      for (int j = 0; j < 8; ++j) {
        #pragma unroll
        for (int i = 0; i < 4; ++i) {
          // ONE VALU slot per element-pair: acc = |k - q| + acc
          asm("v_sad_u32 %0, %1, %2, %0"
              : "+v"(acc[j * 4 + i])
              : "v"(k[i]), "v"(q[j]));
        }
      }
    }

    { // epilogue for iteration I: online softmax update (integer min -> float)
      float vo[4];
      const int vb = I * 512 + w * 32 + ln * 4;
      *(float4*)&vo[0] = *(const float4*)&VoB[vb];   // global, L2-hot
      #pragma unroll
      for (int j = 0; j < 8; ++j) {
        unsigned rmin = umin2(umin2(acc[j*4+0], acc[j*4+1]), umin2(acc[j*4+2], acc[j*4+3]));
        rmin = umin2(rmin, __shfl_xor(rmin, 1));
        rmin = umin2(rmin, __shfl_xor(rmin, 2));
        rmin = umin2(rmin, __shfl_xor(rmin, 4));
        const float rminf = (float)rmin * QIN;                 // min s (true units)
        const float nM = fminf(Mt[j], rminf * rminf);          // min s^2
        const float sc = __builtin_amdgcn_exp2f(CC * (nM - Mt[j])); // inf start -> 0
        const int slot = w * 512 + j * 64 + lane;
        float nm = numL[slot] * sc;
        float dn = denL[slot] * sc;
        Mt[j] = nM;
        const float base = CC * nM;
        #pragma unroll
        for (int i = 0; i < 4; ++i) {
          const float af = (float)acc[j * 4 + i];              // integer s
          const float wgt = __builtin_amdgcn_exp2f(fmaf(-CCI, af * af, base));
          dn += wgt;
          nm = fmaf(wgt, vo[i], nm);
          acc[j * 4 + i] = 0u;
        }
        numL[slot] = nm;
        denL[slot] = dn;
      }
    }
  }

  // publish per-wave Mt (uniform across the 8 ln-lanes of each m)
  if (ln == 0) {
    #pragma unroll
    for (int j = 0; j < 8; ++j)
      MtL[w * 64 + lm * 8 + j] = Mt[j];
  }
  __syncthreads();

  if (tid < 64) {                  // merge the 16 waves' partial softmax states
    const int m = tid;             // m = lm*8 + j  ->  j = m&7, lm = m>>3
    float M = __builtin_inff();
    #pragma unroll
    for (int ww = 0; ww < 16; ++ww) M = fminf(M, MtL[ww * 64 + m]);
    float Ns = 0.f, Ds = 0.f;
    #pragma unroll
    for (int ww = 0; ww < 16; ++ww) {
      const float f = __builtin_amdgcn_exp2f(CC * (M - MtL[ww * 64 + m]));
      float ns = 0.f, ds = 0.f;
      #pragma unroll
      for (int l = 0; l < 8; ++l) {
        ns += numL[ww * 512 + (m & 7) * 64 + (m >> 3) * 8 + l];
        ds += denL[ww * 512 + (m & 7) * 64 + (m >> 3) * 8 + l];
      }
      Ns = fmaf(ns, f, Ns);
      Ds = fmaf(ds, f, Ds);
    }
    out[(size_t)b * NPTS + m0 + m] = Ns / Ds + bo[0];
  }
}

extern "C" void kernel_launch(void* const* d_in, const int* in_sizes, int n_in,
                              void* d_out, int out_size, void* d_ws, size_t ws_size,
                              hipStream_t stream)
{
  const float* coords_f = (const float*)d_in[0];
  const float* values_f = (const float*)d_in[1];
  const float* coords_t = (const float*)d_in[2];
  const float* Wk1 = (const float*)d_in[3];
  const float* bk1 = (const float*)d_in[4];
  const float* Wk2 = (const float*)d_in[5];
  const float* bk2 = (const float*)d_in[6];
  const float* Wq1 = (const float*)d_in[7];
  const float* bq1 = (const float*)d_in[8];
  const float* Wq2 = (const float*)d_in[9];
  const float* bq2 = (const float*)d_in[10];
  const float* Wv1 = (const float*)d_in[11];
  const float* bv1 = (const float*)d_in[12];
  const float* Wv2 = (const float*)d_in[13];
  const float* bv2 = (const float*)d_in[14];
  const float* Wo  = (const float*)d_in[15];
  const float* bo  = (const float*)d_in[16];

  const int B    = in_sizes[0] / (NPTS * 3);
  const int npts = B * NPTS;

  unsigned* KtI = (unsigned*)d_ws;                  // [B][64][N] u32 fixed-point
  unsigned* QtI = KtI + (size_t)B * 64 * NPTS;      // [B][64][M] u32 fixed-point
  float*    VoW = (float*)(QtI + (size_t)B * 64 * NPTS);  // [B][N]

  feat_kernel<<<npts / 64, 256, 0, stream>>>(coords_f, Wk1, bk1, Wk2, bk2, KtI, npts);
  feat_kernel<<<npts / 64, 256, 0, stream>>>(coords_t, Wq1, bq1, Wq2, bq2, QtI, npts);
  vo_kernel<<<npts / 256, 256, 0, stream>>>(values_f, Wv1, bv1, Wv2, bv2, Wo, VoW, npts);
  attn_kernel<<<B * 64, 1024, 0, stream>>>(KtI, QtI, VoW, bo, (float*)d_out);
}

// Round 14
// 195.964 us; speedup vs baseline: 1.2663x; 1.1481x over previous
//
#include <hip/hip_runtime.h>
#include <math.h>

#define NPTS 4096
#define CC  0.7213475204444817f      // log2(e)/2 : exp(-s^2/2) = 2^(-CC*s^2)
#define QSC 524288.0f                // 2^19 fixed-point scale
#define QIN (1.0f / 524288.0f)       // 2^-19
#define CCI (CC * QIN * QIN)         // CC in (integer s)^2 units

__device__ __forceinline__ unsigned umin2(unsigned a, unsigned b) { return a < b ? a : b; }

// ---------------- feature MLP: coords[B,N,3] -> outT[b][h][n] (u32 fixed-point, transposed) ----
__global__ __launch_bounds__(256) void feat_kernel(
    const float* __restrict__ coords, const float* __restrict__ W1,
    const float* __restrict__ b1, const float* __restrict__ W2,
    const float* __restrict__ b2, unsigned* __restrict__ outT, int npts)
{
  __shared__ float sW1[3 * 64], sb1[64], sW2[64 * 64], sb2[64];
  const int tid = threadIdx.x;
  for (int i = tid; i < 192; i += 256) sW1[i] = W1[i];
  if (tid < 64) { sb1[tid] = b1[tid]; sb2[tid] = b2[tid]; }
  for (int i = tid; i < 4096; i += 256) sW2[i] = W2[i];
  __syncthreads();

  const int p  = blockIdx.x * 64 + (tid & 63);   // point index
  const int qh = (tid >> 6) * 16;                // h-quarter handled by this thread
  if (p >= npts) return;
  const float c0 = coords[p * 3 + 0], c1 = coords[p * 3 + 1], c2 = coords[p * 3 + 2];

  float hid[64];
  #pragma unroll
  for (int j = 0; j < 64; ++j)
    hid[j] = fmaxf(0.f, fmaf(c0, sW1[j], fmaf(c1, sW1[64 + j], fmaf(c2, sW1[128 + j], sb1[j]))));

  float acc[16];
  #pragma unroll
  for (int h = 0; h < 16; ++h) acc[h] = sb2[qh + h];
  for (int j = 0; j < 64; ++j) {
    const float hj = hid[j];
    const float4* wrow = (const float4*)&sW2[j * 64 + qh];
    #pragma unroll
    for (int hq = 0; hq < 4; ++hq) {
      float4 wv = wrow[hq];
      acc[hq * 4 + 0] = fmaf(hj, wv.x, acc[hq * 4 + 0]);
      acc[hq * 4 + 1] = fmaf(hj, wv.y, acc[hq * 4 + 1]);
      acc[hq * 4 + 2] = fmaf(hj, wv.z, acc[hq * 4 + 2]);
      acc[hq * 4 + 3] = fmaf(hj, wv.w, acc[hq * 4 + 3]);
    }
  }
  const int b = p / NPTS, n = p % NPTS;
  #pragma unroll
  for (int h = 0; h < 16; ++h)
    outT[(size_t)(b * 64 + qh + h) * NPTS + n] =
        (unsigned)((int)rintf(acc[h] * QSC) + (1 << 30));
}

// ---------------- Vo kernel: Vo[b,n] = MLP_v(values)[b,n,:] . Wo ----------------
__global__ __launch_bounds__(256) void vo_kernel(
    const float* __restrict__ values, const float* __restrict__ Wv1,
    const float* __restrict__ bv1, const float* __restrict__ Wv2,
    const float* __restrict__ bv2, const float* __restrict__ Wo,
    float* __restrict__ VoOut, int npts)
{
  __shared__ float sWvO[64], sW1[64], sb1[64], sc0;
  const int tid = threadIdx.x;
  if (tid < 64) {
    float a = 0.f;
    for (int h = 0; h < 64; ++h) a = fmaf(Wv2[tid * 64 + h], Wo[h], a);
    sWvO[tid] = a;
    sW1[tid] = Wv1[tid];
    sb1[tid] = bv1[tid];
  } else if (tid == 64) {
    float a = 0.f;
    for (int h = 0; h < 64; ++h) a = fmaf(bv2[h], Wo[h], a);
    sc0 = a;
  }
  __syncthreads();
  const int p = blockIdx.x * 256 + tid;
  if (p >= npts) return;
  const float v = values[p];
  float a = sc0;
  #pragma unroll 8
  for (int j = 0; j < 64; ++j)
    a = fmaf(fmaxf(0.f, fmaf(v, sW1[j], sb1[j])), sWvO[j], a);
  VoOut[p] = a;
}

// ---------------- main attention kernel ----------------
// grid: B*64 blocks (one 64-m tile each), 1024 threads (16 waves).
// Round-13 post-mortem: SAD halved VALU issue (VALUBusy 123->74%) but dur
// stayed 210 us -> the wall is memory-instruction count (8192 VMEM + 16384
// LDS b128 per CU serializing with VALU). This round: 8m x 8n SAD tile --
// 64 SADs per 4 mem instr (16:1 vs 10.7:1), halving LDS instrs. Register
// demand ~112 (acc64 + k8 + q8 + Mt8 + addr) under the 128 budget; "+v" on
// v_sad_u32 forces arch-VGPR placement.
__global__ void __launch_bounds__(1024)
attn_kernel(
    const unsigned* __restrict__ Kt, const unsigned* __restrict__ Qt,
    const float* __restrict__ Vo, const float* __restrict__ bo,
    float* __restrict__ out)
{
  __shared__ unsigned Qs[64 * 64];   // [h][m_local]  16 KB (u32 fixed-point)
  __shared__ float MtL[1024];        // [w][m_local]  4 KB
  __shared__ float numL[8192];       // [w][j*64+lane] running numerator 32 KB
  __shared__ float denL[8192];       // [w][j*64+lane] running denominator 32 KB

  const int b    = blockIdx.x >> 6;
  const int m0   = (blockIdx.x & 63) << 6;
  const int tid  = threadIdx.x;
  const int w    = tid >> 6;         // 0..15
  const int lane = tid & 63;
  const int lm = lane >> 3, ln = lane & 7;

  const unsigned* __restrict__ KtB = Kt + (size_t)b * 64 * NPTS;
  const unsigned* __restrict__ QtB = Qt + (size_t)b * 64 * NPTS;
  const float*    __restrict__ VoB = Vo + (size_t)b * NPTS;

  { // stage Q tile into LDS (coalesced uint4); zero own stats
    const int h = tid >> 4, c16 = (tid & 15) * 4;
    *(uint4*)&Qs[h * 64 + c16] = *(const uint4*)&QtB[(size_t)h * NPTS + m0 + c16];
    #pragma unroll
    for (int j = 0; j < 8; ++j) {
      numL[w * 512 + j * 64 + lane] = 0.f;
      denL[w * 512 + j * 64 + lane] = 0.f;
    }
  }
  __syncthreads();

  unsigned acc[64];
  float Mt[8];
  #pragma unroll
  for (int x = 0; x < 64; ++x) acc[x] = 0u;
  #pragma unroll
  for (int j = 0; j < 8; ++j) Mt[j] = __builtin_inff();

  const unsigned* __restrict__ Kb = KtB + w * 64 + ln * 8;  // per-lane K base
  const unsigned* __restrict__ Qb = &Qs[lm * 8];            // per-lane Q base

  for (int I = 0; I < 4; ++I) {          // n-iterations (1024 n each; wave owns 64)
    const unsigned* __restrict__ Kn = Kb + I * 1024;
    #pragma unroll 2
    for (int h = 0; h < 64; ++h) {       // stream over the feature dim
      unsigned q[8], k[8];
      *(uint4*)&k[0] = *(const uint4*)(Kn + (size_t)h * NPTS);      // VMEM, L2-hot
      *(uint4*)&k[4] = *(const uint4*)(Kn + (size_t)h * NPTS + 4);
      *(uint4*)&q[0] = *(const uint4*)(Qb + h * 64);                // LDS
      *(uint4*)&q[4] = *(const uint4*)(Qb + h * 64 + 4);
      #pragma unroll
      for (int j = 0; j < 8; ++j) {
        #pragma unroll
        for (int i = 0; i < 8; ++i) {
          // ONE VALU slot per element-pair: acc = |k - q| + acc
          asm("v_sad_u32 %0, %1, %2, %0"
              : "+v"(acc[j * 8 + i])
              : "v"(k[i]), "v"(q[j]));
        }
      }
    }

    { // epilogue for iteration I: online softmax update (integer min -> float)
      float vo[8];
      const int vb = I * 1024 + w * 64 + ln * 8;
      *(float4*)&vo[0] = *(const float4*)&VoB[vb];   // global, L2-hot
      *(float4*)&vo[4] = *(const float4*)&VoB[vb + 4];
      #pragma unroll
      for (int j = 0; j < 8; ++j) {
        unsigned rmin = umin2(umin2(umin2(acc[j*8+0], acc[j*8+1]), umin2(acc[j*8+2], acc[j*8+3])),
                              umin2(umin2(acc[j*8+4], acc[j*8+5]), umin2(acc[j*8+6], acc[j*8+7])));
        rmin = umin2(rmin, __shfl_xor(rmin, 1));
        rmin = umin2(rmin, __shfl_xor(rmin, 2));
        rmin = umin2(rmin, __shfl_xor(rmin, 4));
        const float rminf = (float)rmin * QIN;                 // min s (true units)
        const float nM = fminf(Mt[j], rminf * rminf);          // min s^2
        const float sc = __builtin_amdgcn_exp2f(CC * (nM - Mt[j])); // inf start -> 0
        const int slot = w * 512 + j * 64 + lane;
        float nm = numL[slot] * sc;
        float dn = denL[slot] * sc;
        Mt[j] = nM;
        const float base = CC * nM;
        #pragma unroll
        for (int i = 0; i < 8; ++i) {
          const float af = (float)acc[j * 8 + i];              // integer s
          const float wgt = __builtin_amdgcn_exp2f(fmaf(-CCI, af * af, base));
          dn += wgt;
          nm = fmaf(wgt, vo[i], nm);
          acc[j * 8 + i] = 0u;
        }
        numL[slot] = nm;
        denL[slot] = dn;
      }
    }
  }

  // publish per-wave Mt (uniform across the 8 ln-lanes of each m)
  if (ln == 0) {
    #pragma unroll
    for (int j = 0; j < 8; ++j)
      MtL[w * 64 + lm * 8 + j] = Mt[j];
  }
  __syncthreads();

  if (tid < 64) {                  // merge the 16 waves' partial softmax states
    const int m = tid;             // m = lm*8 + j  ->  j = m&7, lm = m>>3
    float M = __builtin_inff();
    #pragma unroll
    for (int ww = 0; ww < 16; ++ww) M = fminf(M, MtL[ww * 64 + m]);
    float Ns = 0.f, Ds = 0.f;
    #pragma unroll
    for (int ww = 0; ww < 16; ++ww) {
      const float f = __builtin_amdgcn_exp2f(CC * (M - MtL[ww * 64 + m]));
      float ns = 0.f, ds = 0.f;
      #pragma unroll
      for (int l = 0; l < 8; ++l) {
        ns += numL[ww * 512 + (m & 7) * 64 + (m >> 3) * 8 + l];
        ds += denL[ww * 512 + (m & 7) * 64 + (m >> 3) * 8 + l];
      }
      Ns = fmaf(ns, f, Ns);
      Ds = fmaf(ds, f, Ds);
    }
    out[(size_t)b * NPTS + m0 + m] = Ns / Ds + bo[0];
  }
}

extern "C" void kernel_launch(void* const* d_in, const int* in_sizes, int n_in,
                              void* d_out, int out_size, void* d_ws, size_t ws_size,
                              hipStream_t stream)
{
  const float* coords_f = (const float*)d_in[0];
  const float* values_f = (const float*)d_in[1];
  const float* coords_t = (const float*)d_in[2];
  const float* Wk1 = (const float*)d_in[3];
  const float* bk1 = (const float*)d_in[4];
  const float* Wk2 = (const float*)d_in[5];
  const float* bk2 = (const float*)d_in[6];
  const float* Wq1 = (const float*)d_in[7];
  const float* bq1 = (const float*)d_in[8];
  const float* Wq2 = (const float*)d_in[9];
  const float* bq2 = (const float*)d_in[10];
  const float* Wv1 = (const float*)d_in[11];
  const float* bv1 = (const float*)d_in[12];
  const float* Wv2 = (const float*)d_in[13];
  const float* bv2 = (const float*)d_in[14];
  const float* Wo  = (const float*)d_in[15];
  const float* bo  = (const float*)d_in[16];

  const int B    = in_sizes[0] / (NPTS * 3);
  const int npts = B * NPTS;

  unsigned* KtI = (unsigned*)d_ws;                  // [B][64][N] u32 fixed-point
  unsigned* QtI = KtI + (size_t)B * 64 * NPTS;      // [B][64][M] u32 fixed-point
  float*    VoW = (float*)(QtI + (size_t)B * 64 * NPTS);  // [B][N]

  feat_kernel<<<npts / 64, 256, 0, stream>>>(coords_f, Wk1, bk1, Wk2, bk2, KtI, npts);
  feat_kernel<<<npts / 64, 256, 0, stream>>>(coords_t, Wq1, bq1, Wq2, bq2, QtI, npts);
  vo_kernel<<<npts / 256, 256, 0, stream>>>(values_f, Wv1, bv1, Wv2, bv2, Wo, VoW, npts);
  attn_kernel<<<B * 64, 1024, 0, stream>>>(KtI, QtI, VoW, bo, (float*)d_out);
}